// Round 1
// 229.482 us; speedup vs baseline: 1.1600x; 1.1600x over previous
//
#include <hip/hip_runtime.h>
#include <hip/hip_bf16.h>

// ConvAttention: 4x [conv(1,5)+BN+LReLU(0.3)] -> per-(b,c) attention over W with
// softmax over last axis, + pe residual.  B=16 Cin=32 Cout=64 H=16 W=512.
// fp32 in / fp32 out.  Internals bf16 MFMA, fp32 accumulation.
// R9: attn de-spilled. Evidence: VGPR_Count=64 (128-reg cap at (256,4), split
// 64arch/64acc) + WRITE_SIZE 244MB vs ~105MB ideal => ~145MB scratch spill
// traffic; occupancy measured 37% anyway (=3 blocks/CU).  So: (256,3) ->
// 170-reg cap (3 blocks/CU, same effective occupancy, zero spill), re-add
// pass-B K-frag register cache (bkf[8], -128 ds_read_b128/wave), and XOR-
// swizzle qT/kT (staging-write bank conflict 32-way -> 8-way; reads stay
// free 2-way).  conv_kernel untouched this round (clean A/B).

typedef __attribute__((ext_vector_type(8))) short short8;   // 8 x bf16 (4 VGPR)
typedef __attribute__((ext_vector_type(4))) float floatx4;  // MFMA acc

#define Q_ELEMS 8388608u     // 16*64*16*512 elements per tensor (q/k/v/pe)
#define LOG2E   1.44269504088896340736f

__device__ __forceinline__ float bf2f(unsigned short u) {
    union { unsigned int i; float f; } c; c.i = ((unsigned int)u) << 16; return c.f;
}
__device__ __forceinline__ unsigned short f2bf(float f) {   // RNE
    union { unsigned int i; float f; } c; c.f = f;
    unsigned int r = c.i + 0x7FFFu + ((c.i >> 16) & 1u);
    return (unsigned short)(r >> 16);
}
__device__ __forceinline__ unsigned int pkbf(float lo, float hi) {  // bf16(hi)<<16|bf16(lo)
    __hip_bfloat162 h2 = __float22bfloat162_rn(make_float2(lo, hi));
    union { __hip_bfloat162 h; unsigned int u; } c; c.h = h2; return c.u;
}

// Swizzled ushort offset into a [512][16] bf16 tile stored flat.
// Row w (32 B) has two 16 B groups; group position ^= (w>>2)&1.
// Reads at (w0+n, quad): lanes n and n+8 alias -> 2-way (free).
// Row-writes (staging): 8 distinct 4-bank slots -> 8-way (was 32-way).
__device__ __forceinline__ int qk_off(int w, int g) {
    return (w << 4) + (((g ^ (w >> 2)) & 1) << 3);
}

struct AllIn { const void* p[21]; };

// ---------------------------------------------------------------------------
// Conv kernel: one block per (b, h, w-quarter). Stages x[b,:,h,wq*128±2] once,
// runs all 4 sel GEMMs.  im2col GEMM, M=co(64) N=w(128) K=160, k = t*32+ci.
// Per-lane weight fragment = 40 CONTIGUOUS floats -> 10 float4 loads.
// Epilogue via per-wave LDS tile -> coalesced uint4 bf16 stores to ws.
// sel==0 (q) pre-scaled by log2(e) (LReLU commutes with positive scale).
// ---------------------------------------------------------------------------
__global__ __launch_bounds__(256, 4) void conv_kernel(AllIn in,
                                                      unsigned short* __restrict__ ws_out)
{
    __shared__ unsigned short xt[132][40];    // xt[wl+2][ci]; rows 80B, 10.6 KB
    __shared__ unsigned short Dt[4][16][40];  // per-wave C tile, 5.1 KB (15.7 total)

    const bool isbf = (*(const unsigned int*)in.p[5] == 0x3F803F80u);

    const int tid = threadIdx.x;
    const int blk = blockIdx.x;               // 1024 = 16b * 16h * 4wq
    const int wq = blk & 3, h = (blk >> 2) & 15, b = blk >> 6;
    const int w0g = wq * 128;

    // ---- stage x[b,:,h, w0g-2 .. w0g+129] transposed into LDS (bf16) ----
    {
        const int lw = tid & 63;              // stride-1 lane mapping
        const int cg = tid >> 6;              // ci group 0..3
        for (int it = 0; it < 8; ++it) {
            const int ci = it * 4 + cg;
            const size_t row = ((size_t)(b * 32 + ci) * 16 + h) << 9;
            #pragma unroll
            for (int m = 0; m < 2; ++m) {
                const int w = lw + 64 * m;    // 0..127
                unsigned short e = isbf ? ((const unsigned short*)in.p[0])[row + w0g + w]
                                        : f2bf(((const float*)in.p[0])[row + w0g + w]);
                xt[w + 2][ci] = e;
            }
        }
    }
    if (tid < 128) {                          // halo rows 0,1 and 130,131
        const int ci = tid >> 2, p = tid & 3;
        const int r  = (p < 2) ? p : 128 + p;
        const int gw = w0g + r - 2;
        unsigned short val = 0;
        if (gw >= 0 && gw < 512) {
            const size_t row = ((size_t)(b * 32 + ci) * 16 + h) << 9;
            val = isbf ? ((const unsigned short*)in.p[0])[row + gw]
                       : f2bf(((const float*)in.p[0])[row + gw]);
        }
        xt[r][ci] = val;
    }
    __syncthreads();

    const int lane = tid & 63, wv = tid >> 6;
    const int n = lane & 15, quad = lane >> 4;
    const int co0 = wv * 16;                  // wave's M-tile

    for (int sel = 0; sel < 4; ++sel) {
        // ---- A frags: w[co0+n][quad*8+j][kk] = 40 contiguous elems ----
        short8 afrag[5];
        if (isbf) {
            const unsigned short* wb = (const unsigned short*)in.p[1 + 5 * sel]
                                       + (co0 + n) * 160 + quad * 40;
            #pragma unroll
            for (int p = 0; p < 5; ++p) {
                const uint4 d = *(const uint4*)(wb + p * 8);
                const unsigned short* e = (const unsigned short*)&d;
                #pragma unroll
                for (int t = 0; t < 8; ++t) {
                    const int idx = p * 8 + t;        // = j*5 + kk
                    afrag[idx % 5][idx / 5] = (short)e[t];
                }
            }
        } else {
            const float* wb = (const float*)in.p[1 + 5 * sel]
                              + (co0 + n) * 160 + quad * 40;
            #pragma unroll
            for (int p = 0; p < 10; ++p) {
                const float4 f = *(const float4*)(wb + p * 4);
                const float* e = (const float*)&f;
                #pragma unroll
                for (int t = 0; t < 4; ++t) {
                    const int idx = p * 4 + t;        // = j*5 + kk
                    afrag[idx % 5][idx / 5] = (short)f2bf(e[t]);
                }
            }
        }
        // ---- BN constants (D rows = quad*4+r); q gets the log2e fold ----
        float sc[4], sh[4];
        #pragma unroll
        for (int r = 0; r < 4; ++r) {
            const int co = co0 + quad * 4 + r;
            const void* gp = in.p[2 + 5 * sel];
            const void* bp = in.p[3 + 5 * sel];
            const void* mp = in.p[4 + 5 * sel];
            const void* vp = in.p[5 + 5 * sel];
            float gg = isbf ? bf2f(((const unsigned short*)gp)[co]) : ((const float*)gp)[co];
            float bb = isbf ? bf2f(((const unsigned short*)bp)[co]) : ((const float*)bp)[co];
            float mm = isbf ? bf2f(((const unsigned short*)mp)[co]) : ((const float*)mp)[co];
            float vv = isbf ? bf2f(((const unsigned short*)vp)[co]) : ((const float*)vp)[co];
            sc[r] = gg * rsqrtf(vv + 1e-5f);
            sh[r] = bb - mm * sc[r];
            if (sel == 0) { sc[r] *= LOG2E; sh[r] *= LOG2E; }
        }

        unsigned short* outq = ws_out + (size_t)sel * Q_ELEMS;
        for (int g = 0; g < 4; ++g) {         // 32-w groups within this quarter
            const int w0l = g * 32;
            #pragma unroll
            for (int half = 0; half < 2; ++half) {
                const int w0 = w0l + half * 16;
                floatx4 acc = {0.f, 0.f, 0.f, 0.f};
                #pragma unroll
                for (int kk = 0; kk < 5; ++kk) {
                    short8 bfrag = *(const short8*)&xt[w0 + n + kk][quad * 8];
                    acc = __builtin_amdgcn_mfma_f32_16x16x32_bf16(afrag[kk], bfrag, acc, 0, 0, 0);
                }
                #pragma unroll
                for (int r = 0; r < 4; ++r) {
                    float y = acc[r] * sc[r] + sh[r];
                    y = fmaxf(y, 0.3f * y);                   // LeakyReLU(0.3)
                    Dt[wv][quad * 4 + r][half * 16 + n] = f2bf(y);
                }
            }
            __asm__ volatile("" ::: "memory");
            const uint4 d = *(const uint4*)&Dt[wv][n][quad * 8];
            __asm__ volatile("" ::: "memory");
            *(uint4*)&outq[(((size_t)(b * 64 + co0 + n) * 16 + h) << 9)
                           + w0g + w0l + quad * 8] = d;
        }
    }
}

// ---------------------------------------------------------------------------
// Attention kernel: one block (4 waves) per (b,c) pair, 3 blocks/CU.
//   pass A: l[w] = sum_v exp2(S'[w,v]); S' = Q'^T K (q pre-scaled by log2e)
//   pass B: out[h,v] = sum_w (V[h,w]/l[w]) * exp2(S'[w,v])  + pe[h,v]
// R9: (256,3) -> 170-reg cap.  Measured occupancy at (256,4) was 37% anyway
// (3 blocks/CU effective), but the 128-reg cap forced 64arch+64acc and ~145MB
// of scratch spill traffic (WRITE_SIZE evidence).  With 170 regs: no spill,
// and bkf[8] K-frag cache (32 VGPRs) removes 128 inner-loop ds_read_b128.
// ---------------------------------------------------------------------------
__global__ __launch_bounds__(256, 3) void attn_kernel(const unsigned short* __restrict__ qg,
                                                      const unsigned short* __restrict__ kg,
                                                      const unsigned short* __restrict__ vg,
                                                      const unsigned short* __restrict__ peg,
                                                      float* __restrict__ outg)
{
    __shared__ unsigned short qT[512 * 16];    // qT[w][h] swizzled, 16 KB
    __shared__ unsigned short kT[512 * 16];    // kT[v][h] swizzled, 16 KB
    __shared__ float rcpl[512];                // 1 / l[w]   2 KB
    __shared__ unsigned int Pt[4][16][20];     // per-wave P' tile, 5.12 KB  (39.9 total)

    const int tid = threadIdx.x;
    const int bc = blockIdx.x;                 // 1024 = (b*64 + c)
    const size_t base = (size_t)bc << 13;      // *8192 elems

    const int lane = tid & 63, wv = tid >> 6;

    // ---- stage q,k transposed via in-register v_perm ----
    {
        const int wp = (wv << 7) + (lane << 1);   // wave's w-pair
        unsigned int rq[16], rk[16];
        #pragma unroll
        for (int h = 0; h < 16; ++h) {
            rq[h] = *(const unsigned int*)(qg + base + (h << 9) + wp);
            rk[h] = *(const unsigned int*)(kg + base + (h << 9) + wp);
        }
        unsigned int lo[8], hi[8];
        #pragma unroll
        for (int j = 0; j < 8; ++j) {
            lo[j] = __builtin_amdgcn_perm(rq[2 * j + 1], rq[2 * j], 0x05040100u);
            hi[j] = __builtin_amdgcn_perm(rq[2 * j + 1], rq[2 * j], 0x07060302u);
        }
        *(uint4*)&qT[qk_off(wp, 0)]     = make_uint4(lo[0], lo[1], lo[2], lo[3]);
        *(uint4*)&qT[qk_off(wp, 1)]     = make_uint4(lo[4], lo[5], lo[6], lo[7]);
        *(uint4*)&qT[qk_off(wp + 1, 0)] = make_uint4(hi[0], hi[1], hi[2], hi[3]);
        *(uint4*)&qT[qk_off(wp + 1, 1)] = make_uint4(hi[4], hi[5], hi[6], hi[7]);
        #pragma unroll
        for (int j = 0; j < 8; ++j) {
            lo[j] = __builtin_amdgcn_perm(rk[2 * j + 1], rk[2 * j], 0x05040100u);
            hi[j] = __builtin_amdgcn_perm(rk[2 * j + 1], rk[2 * j], 0x07060302u);
        }
        *(uint4*)&kT[qk_off(wp, 0)]     = make_uint4(lo[0], lo[1], lo[2], lo[3]);
        *(uint4*)&kT[qk_off(wp, 1)]     = make_uint4(lo[4], lo[5], lo[6], lo[7]);
        *(uint4*)&kT[qk_off(wp + 1, 0)] = make_uint4(hi[0], hi[1], hi[2], hi[3]);
        *(uint4*)&kT[qk_off(wp + 1, 1)] = make_uint4(hi[4], hi[5], hi[6], hi[7]);
    }
    __syncthreads();

    const int n = lane & 15, quad = lane >> 4;
    const short8 z8 = {0, 0, 0, 0, 0, 0, 0, 0};
    const floatx4 zf = {0.f, 0.f, 0.f, 0.f};

    // ---- pass A: softmax denominators ----
    for (int s = 0; s < 8; ++s) {
        const int w0 = (wv * 8 + s) * 16;
        short8 aq = (quad < 2) ? *(const short8*)&qT[qk_off(w0 + n, quad)] : z8;  // k=h pad
        float sum[4] = {0.f, 0.f, 0.f, 0.f};
        for (int vt = 0; vt < 32; ++vt) {
            short8 bk = (quad < 2) ? *(const short8*)&kT[qk_off(vt * 16 + n, quad)] : z8;
            floatx4 d = __builtin_amdgcn_mfma_f32_16x16x32_bf16(aq, bk, zf, 0, 0, 0);
            #pragma unroll
            for (int r = 0; r < 4; ++r) sum[r] += __builtin_amdgcn_exp2f(d[r]);
        }
        #pragma unroll
        for (int off = 1; off < 16; off <<= 1) {
            #pragma unroll
            for (int r = 0; r < 4; ++r) sum[r] += __shfl_xor(sum[r], off, 64);
        }
        if (n == 0) {
            #pragma unroll
            for (int r = 0; r < 4; ++r)
                rcpl[w0 + quad * 4 + r] = 1.0f / fmaxf(sum[r], 1e-30f);
        }
    }
    __syncthreads();

    // ---- pass B: wave owns v-range [wv*128, wv*128+128) ----
    const int v0 = wv * 128;

    // K-frag register cache for the wave's v-range (32 VGPRs, reused 16x each)
    short8 bkf[8];
    #pragma unroll
    for (int nt = 0; nt < 8; ++nt)
        bkf[nt] = (quad < 2) ? *(const short8*)&kT[qk_off(v0 + nt * 16 + n, quad)] : z8;

    floatx4 acc[8];
    #pragma unroll
    for (int nt = 0; nt < 8; ++nt) acc[nt] = zf;

    for (int kc = 0; kc < 16; ++kc) {          // w-chunks of 32 (contraction)
        const int w0 = kc * 32;
        short8 aq0 = (quad < 2) ? *(const short8*)&qT[qk_off(w0 + n, quad)] : z8;
        short8 aq1 = (quad < 2) ? *(const short8*)&qT[qk_off(w0 + 16 + n, quad)] : z8;
        // av' = bf16( V[h=n][w0+quad*8+j] * rcpl[w0+quad*8+j] )  -- per-kc fold
        short8 vraw = *(const short8*)(vg + base + ((size_t)n << 9) + w0 + quad * 8);
        const float4 ra = *(const float4*)&rcpl[w0 + quad * 8];
        const float4 rb = *(const float4*)&rcpl[w0 + quad * 8 + 4];
        short8 av;
        av[0] = (short)f2bf(bf2f((unsigned short)vraw[0]) * ra.x);
        av[1] = (short)f2bf(bf2f((unsigned short)vraw[1]) * ra.y);
        av[2] = (short)f2bf(bf2f((unsigned short)vraw[2]) * ra.z);
        av[3] = (short)f2bf(bf2f((unsigned short)vraw[3]) * ra.w);
        av[4] = (short)f2bf(bf2f((unsigned short)vraw[4]) * rb.x);
        av[5] = (short)f2bf(bf2f((unsigned short)vraw[5]) * rb.y);
        av[6] = (short)f2bf(bf2f((unsigned short)vraw[6]) * rb.z);
        av[7] = (short)f2bf(bf2f((unsigned short)vraw[7]) * rb.w);

        #pragma unroll
        for (int nt = 0; nt < 8; ++nt) {
            floatx4 s0 = __builtin_amdgcn_mfma_f32_16x16x32_bf16(aq0, bkf[nt], zf, 0, 0, 0);
            floatx4 s1 = __builtin_amdgcn_mfma_f32_16x16x32_bf16(aq1, bkf[nt], zf, 0, 0, 0);
            // P' = exp2(S'), bf16-packed, via per-wave LDS tile (C->B layout)
            const unsigned int u00 = pkbf(__builtin_amdgcn_exp2f(s0[0]),
                                          __builtin_amdgcn_exp2f(s0[1]));
            const unsigned int u01 = pkbf(__builtin_amdgcn_exp2f(s0[2]),
                                          __builtin_amdgcn_exp2f(s0[3]));
            const unsigned int u10 = pkbf(__builtin_amdgcn_exp2f(s1[0]),
                                          __builtin_amdgcn_exp2f(s1[1]));
            const unsigned int u11 = pkbf(__builtin_amdgcn_exp2f(s1[2]),
                                          __builtin_amdgcn_exp2f(s1[3]));
            Pt[wv][n][quad * 2]         = u00;   // w-local quad*4 + 0..1
            Pt[wv][n][quad * 2 + 1]     = u01;   // w-local quad*4 + 2..3
            Pt[wv][n][8 + quad * 2]     = u10;   // w-local 16+quad*4 + 0..1
            Pt[wv][n][8 + quad * 2 + 1] = u11;   // w-local 16+quad*4 + 2..3
            __asm__ volatile("" ::: "memory");   // no load hoisting past stores
            union { uint4 u; short8 s; } bpc;
            bpc.u = *(const uint4*)&Pt[wv][n][quad * 4];  // B: k=w-local, n=v
            __asm__ volatile("" ::: "memory");
            acc[nt] = __builtin_amdgcn_mfma_f32_16x16x32_bf16(av, bpc.s, acc[nt], 0, 0, 0);
        }
    }

    // ---- epilogue: + pe (bf16 from ws), store fp32 (write-only d_out) ----
    #pragma unroll
    for (int nt = 0; nt < 8; ++nt) {
        #pragma unroll
        for (int r = 0; r < 4; ++r) {
            const int hrow = quad * 4 + r;
            const size_t o = base + ((size_t)hrow << 9) + (v0 + nt * 16 + n);
            outg[o] = acc[nt][r] + bf2f(peg[o]);
        }
    }
}

// ---------------------------------------------------------------------------
extern "C" void kernel_launch(void* const* d_in, const int* in_sizes, int n_in,
                              void* d_out, int out_size, void* d_ws, size_t ws_size,
                              hipStream_t stream)
{
    AllIn ai;
    for (int i = 0; i < 21; ++i) ai.p[i] = d_in[i];

    unsigned short* ws  = (unsigned short*)d_ws;   // q,k,v,pe bf16: exactly 64 MiB
    float* out = (float*)d_out;                    // write-only fp32 output

    conv_kernel<<<1024, 256, 0, stream>>>(ai, ws);
    attn_kernel<<<1024, 256, 0, stream>>>(ws,
                                          ws + (size_t)Q_ELEMS,
                                          ws + 2 * (size_t)Q_ELEMS,
                                          ws + 3 * (size_t)Q_ELEMS,
                                          out);
}

// Round 2
// 220.212 us; speedup vs baseline: 1.2088x; 1.0421x over previous
//
#include <hip/hip_runtime.h>
#include <hip/hip_bf16.h>

// ConvAttention: 4x [conv(1,5)+BN+LReLU(0.3)] -> per-(b,c) attention over W with
// softmax over last axis, + pe residual.  B=16 Cin=32 Cout=64 H=16 W=512.
// fp32 in / fp32 out.  Internals bf16 MFMA, fp32 accumulation.
// R10: attn merged single-pass.  R9 counters: VALUBusy 64%, MfmaUtil 17%,
// HBM 8% -> VALU-throughput-bound.  Old 2-pass recomputed S and exp2(S)
// twice (2048 exp2/wave at 1/4 rate ~= 16K cy).  New: chunk w by 32; per
// chunk compute P~=exp2(S') once, stash shuffled B-frags in regs (bpcu[8]),
// row-sum l[w] from the same exp2 results (shfl over n + cross-wave LDS,
// parity double-buffered, ONE barrier/chunk), scale V-operand by 1/l, PV.
// exp2 2048->1024, MFMA 640->384 per wave.  conv untouched (clean A/B).

typedef __attribute__((ext_vector_type(8))) short short8;   // 8 x bf16 (4 VGPR)
typedef __attribute__((ext_vector_type(4))) float floatx4;  // MFMA acc

#define Q_ELEMS 8388608u     // 16*64*16*512 elements per tensor (q/k/v/pe)
#define LOG2E   1.44269504088896340736f

__device__ __forceinline__ float bf2f(unsigned short u) {
    union { unsigned int i; float f; } c; c.i = ((unsigned int)u) << 16; return c.f;
}
__device__ __forceinline__ unsigned short f2bf(float f) {   // RNE
    union { unsigned int i; float f; } c; c.f = f;
    unsigned int r = c.i + 0x7FFFu + ((c.i >> 16) & 1u);
    return (unsigned short)(r >> 16);
}
__device__ __forceinline__ unsigned int pkbf(float lo, float hi) {  // bf16(hi)<<16|bf16(lo)
    __hip_bfloat162 h2 = __float22bfloat162_rn(make_float2(lo, hi));
    union { __hip_bfloat162 h; unsigned int u; } c; c.h = h2; return c.u;
}

// Swizzled ushort offset into a [512][16] bf16 tile stored flat.
// Row w (32 B) has two 16 B groups; group position ^= (w>>2)&1.
// Reads at (w0+n, quad): lanes n and n+8 alias -> 2-way (free).
// Row-writes (staging): 8 distinct 4-bank slots -> 8-way (was 32-way).
__device__ __forceinline__ int qk_off(int w, int g) {
    return (w << 4) + (((g ^ (w >> 2)) & 1) << 3);
}

struct AllIn { const void* p[21]; };

// ---------------------------------------------------------------------------
// Conv kernel: one block per (b, h, w-quarter). Stages x[b,:,h,wq*128±2] once,
// runs all 4 sel GEMMs.  im2col GEMM, M=co(64) N=w(128) K=160, k = t*32+ci.
// Per-lane weight fragment = 40 CONTIGUOUS floats -> 10 float4 loads.
// Epilogue via per-wave LDS tile -> coalesced uint4 bf16 stores to ws.
// sel==0 (q) pre-scaled by log2(e) (LReLU commutes with positive scale).
// ---------------------------------------------------------------------------
__global__ __launch_bounds__(256, 4) void conv_kernel(AllIn in,
                                                      unsigned short* __restrict__ ws_out)
{
    __shared__ unsigned short xt[132][40];    // xt[wl+2][ci]; rows 80B, 10.6 KB
    __shared__ unsigned short Dt[4][16][40];  // per-wave C tile, 5.1 KB (15.7 total)

    const bool isbf = (*(const unsigned int*)in.p[5] == 0x3F803F80u);

    const int tid = threadIdx.x;
    const int blk = blockIdx.x;               // 1024 = 16b * 16h * 4wq
    const int wq = blk & 3, h = (blk >> 2) & 15, b = blk >> 6;
    const int w0g = wq * 128;

    // ---- stage x[b,:,h, w0g-2 .. w0g+129] transposed into LDS (bf16) ----
    {
        const int lw = tid & 63;              // stride-1 lane mapping
        const int cg = tid >> 6;              // ci group 0..3
        for (int it = 0; it < 8; ++it) {
            const int ci = it * 4 + cg;
            const size_t row = ((size_t)(b * 32 + ci) * 16 + h) << 9;
            #pragma unroll
            for (int m = 0; m < 2; ++m) {
                const int w = lw + 64 * m;    // 0..127
                unsigned short e = isbf ? ((const unsigned short*)in.p[0])[row + w0g + w]
                                        : f2bf(((const float*)in.p[0])[row + w0g + w]);
                xt[w + 2][ci] = e;
            }
        }
    }
    if (tid < 128) {                          // halo rows 0,1 and 130,131
        const int ci = tid >> 2, p = tid & 3;
        const int r  = (p < 2) ? p : 128 + p;
        const int gw = w0g + r - 2;
        unsigned short val = 0;
        if (gw >= 0 && gw < 512) {
            const size_t row = ((size_t)(b * 32 + ci) * 16 + h) << 9;
            val = isbf ? ((const unsigned short*)in.p[0])[row + gw]
                       : f2bf(((const float*)in.p[0])[row + gw]);
        }
        xt[r][ci] = val;
    }
    __syncthreads();

    const int lane = tid & 63, wv = tid >> 6;
    const int n = lane & 15, quad = lane >> 4;
    const int co0 = wv * 16;                  // wave's M-tile

    for (int sel = 0; sel < 4; ++sel) {
        // ---- A frags: w[co0+n][quad*8+j][kk] = 40 contiguous elems ----
        short8 afrag[5];
        if (isbf) {
            const unsigned short* wb = (const unsigned short*)in.p[1 + 5 * sel]
                                       + (co0 + n) * 160 + quad * 40;
            #pragma unroll
            for (int p = 0; p < 5; ++p) {
                const uint4 d = *(const uint4*)(wb + p * 8);
                const unsigned short* e = (const unsigned short*)&d;
                #pragma unroll
                for (int t = 0; t < 8; ++t) {
                    const int idx = p * 8 + t;        // = j*5 + kk
                    afrag[idx % 5][idx / 5] = (short)e[t];
                }
            }
        } else {
            const float* wb = (const float*)in.p[1 + 5 * sel]
                              + (co0 + n) * 160 + quad * 40;
            #pragma unroll
            for (int p = 0; p < 10; ++p) {
                const float4 f = *(const float4*)(wb + p * 4);
                const float* e = (const float*)&f;
                #pragma unroll
                for (int t = 0; t < 4; ++t) {
                    const int idx = p * 4 + t;        // = j*5 + kk
                    afrag[idx % 5][idx / 5] = (short)f2bf(e[t]);
                }
            }
        }
        // ---- BN constants (D rows = quad*4+r); q gets the log2e fold ----
        float sc[4], sh[4];
        #pragma unroll
        for (int r = 0; r < 4; ++r) {
            const int co = co0 + quad * 4 + r;
            const void* gp = in.p[2 + 5 * sel];
            const void* bp = in.p[3 + 5 * sel];
            const void* mp = in.p[4 + 5 * sel];
            const void* vp = in.p[5 + 5 * sel];
            float gg = isbf ? bf2f(((const unsigned short*)gp)[co]) : ((const float*)gp)[co];
            float bb = isbf ? bf2f(((const unsigned short*)bp)[co]) : ((const float*)bp)[co];
            float mm = isbf ? bf2f(((const unsigned short*)mp)[co]) : ((const float*)mp)[co];
            float vv = isbf ? bf2f(((const unsigned short*)vp)[co]) : ((const float*)vp)[co];
            sc[r] = gg * rsqrtf(vv + 1e-5f);
            sh[r] = bb - mm * sc[r];
            if (sel == 0) { sc[r] *= LOG2E; sh[r] *= LOG2E; }
        }

        unsigned short* outq = ws_out + (size_t)sel * Q_ELEMS;
        for (int g = 0; g < 4; ++g) {         // 32-w groups within this quarter
            const int w0l = g * 32;
            #pragma unroll
            for (int half = 0; half < 2; ++half) {
                const int w0 = w0l + half * 16;
                floatx4 acc = {0.f, 0.f, 0.f, 0.f};
                #pragma unroll
                for (int kk = 0; kk < 5; ++kk) {
                    short8 bfrag = *(const short8*)&xt[w0 + n + kk][quad * 8];
                    acc = __builtin_amdgcn_mfma_f32_16x16x32_bf16(afrag[kk], bfrag, acc, 0, 0, 0);
                }
                #pragma unroll
                for (int r = 0; r < 4; ++r) {
                    float y = acc[r] * sc[r] + sh[r];
                    y = fmaxf(y, 0.3f * y);                   // LeakyReLU(0.3)
                    Dt[wv][quad * 4 + r][half * 16 + n] = f2bf(y);
                }
            }
            __asm__ volatile("" ::: "memory");
            const uint4 d = *(const uint4*)&Dt[wv][n][quad * 8];
            __asm__ volatile("" ::: "memory");
            *(uint4*)&outq[(((size_t)(b * 64 + co0 + n) * 16 + h) << 9)
                           + w0g + w0l + quad * 8] = d;
        }
    }
}

// ---------------------------------------------------------------------------
// Attention kernel: one block (4 waves) per (b,c) pair.
// Merged single pass over w-chunks of 32:
//   per chunk: P~[w,v] = exp2(S'[w,v]) computed ONCE (wave owns v-range 128),
//   B-frags stashed in regs; l[w] = sum_v P~ via in-reg adds + shfl over n +
//   cross-wave LDS (parity dbuf, 1 barrier); then av = bf16(V[h,w]/l[w]) and
//   acc[nt] += av x P~.   out[h,v] = acc + pe[h,v].
// ---------------------------------------------------------------------------
__global__ __launch_bounds__(256, 3) void attn_kernel(const unsigned short* __restrict__ qg,
                                                      const unsigned short* __restrict__ kg,
                                                      const unsigned short* __restrict__ vg,
                                                      const unsigned short* __restrict__ peg,
                                                      float* __restrict__ outg)
{
    __shared__ unsigned short qT[512 * 16];    // qT[w][h] swizzled, 16 KB
    __shared__ unsigned short kT[512 * 16];    // kT[v][h] swizzled, 16 KB
    __shared__ unsigned int Pt[4][16][20];     // per-wave P' tile, 5.12 KB
    __shared__ float lpartT[2][32][4];         // [chunk parity][w-local][wave], 1 KB

    const int tid = threadIdx.x;
    const int bc = blockIdx.x;                 // 1024 = (b*64 + c)
    const size_t base = (size_t)bc << 13;      // *8192 elems

    const int lane = tid & 63, wv = tid >> 6;

    // ---- stage q,k transposed via in-register v_perm ----
    {
        const int wp = (wv << 7) + (lane << 1);   // wave's w-pair
        unsigned int rq[16], rk[16];
        #pragma unroll
        for (int h = 0; h < 16; ++h) {
            rq[h] = *(const unsigned int*)(qg + base + (h << 9) + wp);
            rk[h] = *(const unsigned int*)(kg + base + (h << 9) + wp);
        }
        unsigned int lo[8], hi[8];
        #pragma unroll
        for (int j = 0; j < 8; ++j) {
            lo[j] = __builtin_amdgcn_perm(rq[2 * j + 1], rq[2 * j], 0x05040100u);
            hi[j] = __builtin_amdgcn_perm(rq[2 * j + 1], rq[2 * j], 0x07060302u);
        }
        *(uint4*)&qT[qk_off(wp, 0)]     = make_uint4(lo[0], lo[1], lo[2], lo[3]);
        *(uint4*)&qT[qk_off(wp, 1)]     = make_uint4(lo[4], lo[5], lo[6], lo[7]);
        *(uint4*)&qT[qk_off(wp + 1, 0)] = make_uint4(hi[0], hi[1], hi[2], hi[3]);
        *(uint4*)&qT[qk_off(wp + 1, 1)] = make_uint4(hi[4], hi[5], hi[6], hi[7]);
        #pragma unroll
        for (int j = 0; j < 8; ++j) {
            lo[j] = __builtin_amdgcn_perm(rk[2 * j + 1], rk[2 * j], 0x05040100u);
            hi[j] = __builtin_amdgcn_perm(rk[2 * j + 1], rk[2 * j], 0x07060302u);
        }
        *(uint4*)&kT[qk_off(wp, 0)]     = make_uint4(lo[0], lo[1], lo[2], lo[3]);
        *(uint4*)&kT[qk_off(wp, 1)]     = make_uint4(lo[4], lo[5], lo[6], lo[7]);
        *(uint4*)&kT[qk_off(wp + 1, 0)] = make_uint4(hi[0], hi[1], hi[2], hi[3]);
        *(uint4*)&kT[qk_off(wp + 1, 1)] = make_uint4(hi[4], hi[5], hi[6], hi[7]);
    }
    __syncthreads();

    const int n = lane & 15, quad = lane >> 4;
    const short8 z8 = {0, 0, 0, 0, 0, 0, 0, 0};
    const floatx4 zf = {0.f, 0.f, 0.f, 0.f};

    // ---- wave owns v-range [wv*128, wv*128+128); K-frag cache 32 VGPR ----
    const int v0 = wv * 128;
    short8 bkf[8];
    #pragma unroll
    for (int nt = 0; nt < 8; ++nt)
        bkf[nt] = (quad < 2) ? *(const short8*)&kT[qk_off(v0 + nt * 16 + n, quad)] : z8;

    floatx4 acc[8];
    #pragma unroll
    for (int nt = 0; nt < 8; ++nt) acc[nt] = zf;

    for (int kc = 0; kc < 16; ++kc) {          // w-chunks of 32 (contraction)
        const int w0 = kc * 32;
        const int pb = kc & 1;
        short8 aq0 = (quad < 2) ? *(const short8*)&qT[qk_off(w0 + n, quad)] : z8;
        short8 aq1 = (quad < 2) ? *(const short8*)&qT[qk_off(w0 + 16 + n, quad)] : z8;
        // V[h=n][w0 + quad*8 + j]  (issued early; consumed after the barrier)
        short8 vraw = *(const short8*)(vg + base + ((size_t)n << 9) + w0 + quad * 8);

        // ---- phase 1: P~ once; stash B-frags; accumulate row-sums ----
        float sum[8] = {0.f, 0.f, 0.f, 0.f, 0.f, 0.f, 0.f, 0.f};
        uint4 bpcu[8];
        #pragma unroll
        for (int nt = 0; nt < 8; ++nt) {
            floatx4 s0 = __builtin_amdgcn_mfma_f32_16x16x32_bf16(aq0, bkf[nt], zf, 0, 0, 0);
            floatx4 s1 = __builtin_amdgcn_mfma_f32_16x16x32_bf16(aq1, bkf[nt], zf, 0, 0, 0);
            const float e00 = __builtin_amdgcn_exp2f(s0[0]);
            const float e01 = __builtin_amdgcn_exp2f(s0[1]);
            const float e02 = __builtin_amdgcn_exp2f(s0[2]);
            const float e03 = __builtin_amdgcn_exp2f(s0[3]);
            const float e10 = __builtin_amdgcn_exp2f(s1[0]);
            const float e11 = __builtin_amdgcn_exp2f(s1[1]);
            const float e12 = __builtin_amdgcn_exp2f(s1[2]);
            const float e13 = __builtin_amdgcn_exp2f(s1[3]);
            sum[0] += e00; sum[1] += e01; sum[2] += e02; sum[3] += e03;
            sum[4] += e10; sum[5] += e11; sum[6] += e12; sum[7] += e13;
            // rows quad*4+r (lo) / 16+quad*4+r (hi), col v = nt*16+n
            Pt[wv][n][quad * 2]         = pkbf(e00, e01);
            Pt[wv][n][quad * 2 + 1]     = pkbf(e02, e03);
            Pt[wv][n][8 + quad * 2]     = pkbf(e10, e11);
            Pt[wv][n][8 + quad * 2 + 1] = pkbf(e12, e13);
            __asm__ volatile("" ::: "memory");   // no load hoisting past stores
            bpcu[nt] = *(const uint4*)&Pt[wv][n][quad * 4];  // B: k=w-local, n=v
            __asm__ volatile("" ::: "memory");
        }
        // reduce row-sums over the 16 n-lanes (quads hold disjoint rows)
        #pragma unroll
        for (int off = 1; off < 16; off <<= 1) {
            #pragma unroll
            for (int r = 0; r < 8; ++r) sum[r] += __shfl_xor(sum[r], off, 64);
        }
        if (n == 0) {
            #pragma unroll
            for (int r = 0; r < 4; ++r) {
                lpartT[pb][quad * 4 + r][wv]      = sum[r];
                lpartT[pb][16 + quad * 4 + r][wv] = sum[4 + r];
            }
        }
        __syncthreads();

        // ---- phase 2: denominators (redundant per lane), av, PV ----
        float rc[8];
        #pragma unroll
        for (int j = 0; j < 8; ++j) {
            const float4 t = *(const float4*)&lpartT[pb][quad * 8 + j][0];
            rc[j] = 1.0f / fmaxf(t.x + t.y + t.z + t.w, 1e-30f);
        }
        union { short8 s; unsigned int u[4]; } av;
        #pragma unroll
        for (int j = 0; j < 4; ++j)
            av.u[j] = pkbf(bf2f((unsigned short)vraw[2 * j]) * rc[2 * j],
                           bf2f((unsigned short)vraw[2 * j + 1]) * rc[2 * j + 1]);
        #pragma unroll
        for (int nt = 0; nt < 8; ++nt) {
            union { uint4 u; short8 s; } bpc; bpc.u = bpcu[nt];
            acc[nt] = __builtin_amdgcn_mfma_f32_16x16x32_bf16(av.s, bpc.s, acc[nt], 0, 0, 0);
        }
    }

    // ---- epilogue: + pe (bf16 from ws), store fp32 (write-only d_out) ----
    #pragma unroll
    for (int nt = 0; nt < 8; ++nt) {
        #pragma unroll
        for (int r = 0; r < 4; ++r) {
            const int hrow = quad * 4 + r;
            const size_t o = base + ((size_t)hrow << 9) + (v0 + nt * 16 + n);
            outg[o] = acc[nt][r] + bf2f(peg[o]);
        }
    }
}

// ---------------------------------------------------------------------------
extern "C" void kernel_launch(void* const* d_in, const int* in_sizes, int n_in,
                              void* d_out, int out_size, void* d_ws, size_t ws_size,
                              hipStream_t stream)
{
    AllIn ai;
    for (int i = 0; i < 21; ++i) ai.p[i] = d_in[i];

    unsigned short* ws  = (unsigned short*)d_ws;   // q,k,v,pe bf16: exactly 64 MiB
    float* out = (float*)d_out;                    // write-only fp32 output

    conv_kernel<<<1024, 256, 0, stream>>>(ai, ws);
    attn_kernel<<<1024, 256, 0, stream>>>(ws,
                                          ws + (size_t)Q_ELEMS,
                                          ws + 2 * (size_t)Q_ELEMS,
                                          ws + 3 * (size_t)Q_ELEMS,
                                          out);
}

// Round 3
// 215.104 us; speedup vs baseline: 1.2375x; 1.0237x over previous
//
#include <hip/hip_runtime.h>
#include <hip/hip_bf16.h>

// ConvAttention: 4x [conv(1,5)+BN+LReLU(0.3)] -> per-(b,c) attention over W with
// softmax over last axis, + pe residual.  B=16 Cin=32 Cout=64 H=16 W=512.
// fp32 in / fp32 out.  Internals bf16 MFMA, fp32 accumulation.
// R11: attn software-pipelined.  R10 counters: dur only -9% despite -40% work;
// VALUBusy fell 64->61 with MfmaUtil 17->11 => post-barrier serialization
// (every wave stalls on lpart read + rcp right after each of 16 barriers).
// Fix: phase2(kc-1) [lpart/rcp/av/PV] runs interleaved with phase1(kc)
// [16 MFMA + 64 exp2 of independent work] after the barrier; P-frags and
// vraw double-buffered in named regs (bpA/bpB, vrA/vrB).  Also: Pt writes
// b32x4 -> b64x2 (bank arithmetic: (20n+2q)%32 put 4 lanes on 16 even banks
// = the measured 6400 conflict-cy/block; b64 positions (10n+q)%16 enumerate
// to uniform 4 lanes/position = conflict-free), and v_rcp_f32 via
// __builtin_amdgcn_rcpf (absmax budget 0.03 >> 1ulp).  conv untouched.

typedef __attribute__((ext_vector_type(8))) short short8;   // 8 x bf16 (4 VGPR)
typedef __attribute__((ext_vector_type(4))) float floatx4;  // MFMA acc

#define Q_ELEMS 8388608u     // 16*64*16*512 elements per tensor (q/k/v/pe)
#define LOG2E   1.44269504088896340736f

__device__ __forceinline__ float bf2f(unsigned short u) {
    union { unsigned int i; float f; } c; c.i = ((unsigned int)u) << 16; return c.f;
}
__device__ __forceinline__ unsigned short f2bf(float f) {   // RNE
    union { unsigned int i; float f; } c; c.f = f;
    unsigned int r = c.i + 0x7FFFu + ((c.i >> 16) & 1u);
    return (unsigned short)(r >> 16);
}
__device__ __forceinline__ unsigned int pkbf(float lo, float hi) {  // bf16(hi)<<16|bf16(lo)
    __hip_bfloat162 h2 = __float22bfloat162_rn(make_float2(lo, hi));
    union { __hip_bfloat162 h; unsigned int u; } c; c.h = h2; return c.u;
}

// Swizzled ushort offset into a [512][16] bf16 tile stored flat.
// Row w (32 B) has two 16 B groups; group position ^= (w>>2)&1.
__device__ __forceinline__ int qk_off(int w, int g) {
    return (w << 4) + (((g ^ (w >> 2)) & 1) << 3);
}

struct AllIn { const void* p[21]; };

// ---------------------------------------------------------------------------
// Conv kernel: one block per (b, h, w-quarter). Stages x[b,:,h,wq*128±2] once,
// runs all 4 sel GEMMs.  im2col GEMM, M=co(64) N=w(128) K=160, k = t*32+ci.
// sel==0 (q) pre-scaled by log2(e) (LReLU commutes with positive scale).
// ---------------------------------------------------------------------------
__global__ __launch_bounds__(256, 4) void conv_kernel(AllIn in,
                                                      unsigned short* __restrict__ ws_out)
{
    __shared__ unsigned short xt[132][40];    // xt[wl+2][ci]; rows 80B, 10.6 KB
    __shared__ unsigned short Dt[4][16][40];  // per-wave C tile, 5.1 KB (15.7 total)

    const bool isbf = (*(const unsigned int*)in.p[5] == 0x3F803F80u);

    const int tid = threadIdx.x;
    const int blk = blockIdx.x;               // 1024 = 16b * 16h * 4wq
    const int wq = blk & 3, h = (blk >> 2) & 15, b = blk >> 6;
    const int w0g = wq * 128;

    // ---- stage x[b,:,h, w0g-2 .. w0g+129] transposed into LDS (bf16) ----
    {
        const int lw = tid & 63;              // stride-1 lane mapping
        const int cg = tid >> 6;              // ci group 0..3
        for (int it = 0; it < 8; ++it) {
            const int ci = it * 4 + cg;
            const size_t row = ((size_t)(b * 32 + ci) * 16 + h) << 9;
            #pragma unroll
            for (int m = 0; m < 2; ++m) {
                const int w = lw + 64 * m;    // 0..127
                unsigned short e = isbf ? ((const unsigned short*)in.p[0])[row + w0g + w]
                                        : f2bf(((const float*)in.p[0])[row + w0g + w]);
                xt[w + 2][ci] = e;
            }
        }
    }
    if (tid < 128) {                          // halo rows 0,1 and 130,131
        const int ci = tid >> 2, p = tid & 3;
        const int r  = (p < 2) ? p : 128 + p;
        const int gw = w0g + r - 2;
        unsigned short val = 0;
        if (gw >= 0 && gw < 512) {
            const size_t row = ((size_t)(b * 32 + ci) * 16 + h) << 9;
            val = isbf ? ((const unsigned short*)in.p[0])[row + gw]
                       : f2bf(((const float*)in.p[0])[row + gw]);
        }
        xt[r][ci] = val;
    }
    __syncthreads();

    const int lane = tid & 63, wv = tid >> 6;
    const int n = lane & 15, quad = lane >> 4;
    const int co0 = wv * 16;                  // wave's M-tile

    for (int sel = 0; sel < 4; ++sel) {
        // ---- A frags: w[co0+n][quad*8+j][kk] = 40 contiguous elems ----
        short8 afrag[5];
        if (isbf) {
            const unsigned short* wb = (const unsigned short*)in.p[1 + 5 * sel]
                                       + (co0 + n) * 160 + quad * 40;
            #pragma unroll
            for (int p = 0; p < 5; ++p) {
                const uint4 d = *(const uint4*)(wb + p * 8);
                const unsigned short* e = (const unsigned short*)&d;
                #pragma unroll
                for (int t = 0; t < 8; ++t) {
                    const int idx = p * 8 + t;        // = j*5 + kk
                    afrag[idx % 5][idx / 5] = (short)e[t];
                }
            }
        } else {
            const float* wb = (const float*)in.p[1 + 5 * sel]
                              + (co0 + n) * 160 + quad * 40;
            #pragma unroll
            for (int p = 0; p < 10; ++p) {
                const float4 f = *(const float4*)(wb + p * 4);
                const float* e = (const float*)&f;
                #pragma unroll
                for (int t = 0; t < 4; ++t) {
                    const int idx = p * 4 + t;        // = j*5 + kk
                    afrag[idx % 5][idx / 5] = (short)f2bf(e[t]);
                }
            }
        }
        // ---- BN constants (D rows = quad*4+r); q gets the log2e fold ----
        float sc[4], sh[4];
        #pragma unroll
        for (int r = 0; r < 4; ++r) {
            const int co = co0 + quad * 4 + r;
            const void* gp = in.p[2 + 5 * sel];
            const void* bp = in.p[3 + 5 * sel];
            const void* mp = in.p[4 + 5 * sel];
            const void* vp = in.p[5 + 5 * sel];
            float gg = isbf ? bf2f(((const unsigned short*)gp)[co]) : ((const float*)gp)[co];
            float bb = isbf ? bf2f(((const unsigned short*)bp)[co]) : ((const float*)bp)[co];
            float mm = isbf ? bf2f(((const unsigned short*)mp)[co]) : ((const float*)mp)[co];
            float vv = isbf ? bf2f(((const unsigned short*)vp)[co]) : ((const float*)vp)[co];
            sc[r] = gg * rsqrtf(vv + 1e-5f);
            sh[r] = bb - mm * sc[r];
            if (sel == 0) { sc[r] *= LOG2E; sh[r] *= LOG2E; }
        }

        unsigned short* outq = ws_out + (size_t)sel * Q_ELEMS;
        for (int g = 0; g < 4; ++g) {         // 32-w groups within this quarter
            const int w0l = g * 32;
            #pragma unroll
            for (int half = 0; half < 2; ++half) {
                const int w0 = w0l + half * 16;
                floatx4 acc = {0.f, 0.f, 0.f, 0.f};
                #pragma unroll
                for (int kk = 0; kk < 5; ++kk) {
                    short8 bfrag = *(const short8*)&xt[w0 + n + kk][quad * 8];
                    acc = __builtin_amdgcn_mfma_f32_16x16x32_bf16(afrag[kk], bfrag, acc, 0, 0, 0);
                }
                #pragma unroll
                for (int r = 0; r < 4; ++r) {
                    float y = acc[r] * sc[r] + sh[r];
                    y = fmaxf(y, 0.3f * y);                   // LeakyReLU(0.3)
                    Dt[wv][quad * 4 + r][half * 16 + n] = f2bf(y);
                }
            }
            __asm__ volatile("" ::: "memory");
            const uint4 d = *(const uint4*)&Dt[wv][n][quad * 8];
            __asm__ volatile("" ::: "memory");
            *(uint4*)&outq[(((size_t)(b * 64 + co0 + n) * 16 + h) << 9)
                           + w0g + w0l + quad * 8] = d;
        }
    }
}

// ---------------------------------------------------------------------------
// Attention kernel: one block (4 waves) per (b,c) pair, software-pipelined.
// Per w-chunk kc (32 w's):
//   PHASE1(kc): S' = Q'^T K (16 MFMA), P~ = exp2(S') ONCE, b64 pack -> Pt ->
//               B-frags to regs (bp*), row-sums in regs; V chunk prefetch.
//   PUBLISH(kc): shfl-reduce sums over n-lanes, write lpart[kc&1] (n==0).
//   PHASE2(kc-1): lpart[(kc-1)&1] read + rcp + av pack + 8 PV MFMA -- runs
//               AFTER the barrier but hidden under PHASE1(kc)'s MFMA/exp2.
// One barrier per chunk; parity double-buffer makes write(kc+1) safe vs
// read(kc-1) (write sits strictly after the intervening barrier).
// ---------------------------------------------------------------------------
__global__ __launch_bounds__(256, 3) void attn_kernel(const unsigned short* __restrict__ qg,
                                                      const unsigned short* __restrict__ kg,
                                                      const unsigned short* __restrict__ vg,
                                                      const unsigned short* __restrict__ peg,
                                                      float* __restrict__ outg)
{
    __shared__ unsigned short qT[512 * 16];    // qT[w][h] swizzled, 16 KB
    __shared__ unsigned short kT[512 * 16];    // kT[v][h] swizzled, 16 KB
    __shared__ unsigned int Pt[4][16][20];     // per-wave P' tile, 5.12 KB
    __shared__ float lpartT[2][32][4];         // [parity][w-local][wave], 1 KB

    const int tid = threadIdx.x;
    const int bc = blockIdx.x;                 // 1024 = (b*64 + c)
    const size_t base = (size_t)bc << 13;      // *8192 elems

    const int lane = tid & 63, wv = tid >> 6;

    // ---- stage q,k transposed via in-register v_perm ----
    {
        const int wp = (wv << 7) + (lane << 1);   // wave's w-pair
        unsigned int rq[16], rk[16];
        #pragma unroll
        for (int h = 0; h < 16; ++h) {
            rq[h] = *(const unsigned int*)(qg + base + (h << 9) + wp);
            rk[h] = *(const unsigned int*)(kg + base + (h << 9) + wp);
        }
        unsigned int lo[8], hi[8];
        #pragma unroll
        for (int j = 0; j < 8; ++j) {
            lo[j] = __builtin_amdgcn_perm(rq[2 * j + 1], rq[2 * j], 0x05040100u);
            hi[j] = __builtin_amdgcn_perm(rq[2 * j + 1], rq[2 * j], 0x07060302u);
        }
        *(uint4*)&qT[qk_off(wp, 0)]     = make_uint4(lo[0], lo[1], lo[2], lo[3]);
        *(uint4*)&qT[qk_off(wp, 1)]     = make_uint4(lo[4], lo[5], lo[6], lo[7]);
        *(uint4*)&qT[qk_off(wp + 1, 0)] = make_uint4(hi[0], hi[1], hi[2], hi[3]);
        *(uint4*)&qT[qk_off(wp + 1, 1)] = make_uint4(hi[4], hi[5], hi[6], hi[7]);
        #pragma unroll
        for (int j = 0; j < 8; ++j) {
            lo[j] = __builtin_amdgcn_perm(rk[2 * j + 1], rk[2 * j], 0x05040100u);
            hi[j] = __builtin_amdgcn_perm(rk[2 * j + 1], rk[2 * j], 0x07060302u);
        }
        *(uint4*)&kT[qk_off(wp, 0)]     = make_uint4(lo[0], lo[1], lo[2], lo[3]);
        *(uint4*)&kT[qk_off(wp, 1)]     = make_uint4(lo[4], lo[5], lo[6], lo[7]);
        *(uint4*)&kT[qk_off(wp + 1, 0)] = make_uint4(hi[0], hi[1], hi[2], hi[3]);
        *(uint4*)&kT[qk_off(wp + 1, 1)] = make_uint4(hi[4], hi[5], hi[6], hi[7]);
    }
    __syncthreads();

    const int n = lane & 15, quad = lane >> 4;
    const short8 z8 = {0, 0, 0, 0, 0, 0, 0, 0};
    const floatx4 zf = {0.f, 0.f, 0.f, 0.f};

    // ---- wave owns v-range [wv*128, wv*128+128); K-frag cache 32 VGPR ----
    const int v0 = wv * 128;
    short8 bkf[8];
    #pragma unroll
    for (int nt = 0; nt < 8; ++nt)
        bkf[nt] = (quad < 2) ? *(const short8*)&kT[qk_off(v0 + nt * 16 + n, quad)] : z8;

    floatx4 acc[8];
    #pragma unroll
    for (int nt = 0; nt < 8; ++nt) acc[nt] = zf;

    uint4 bpA[8], bpB[8];          // P-fragment double buffer (named: rule #20)
    short8 vrA, vrB;               // V-chunk double buffer

#define PHASE1(KC, BP, VR, SUM)                                                      \
    {                                                                                \
        const int w0_ = (KC) * 32;                                                   \
        short8 aq0 = (quad < 2) ? *(const short8*)&qT[qk_off(w0_ + n, quad)] : z8;   \
        short8 aq1 = (quad < 2) ? *(const short8*)&qT[qk_off(w0_ + 16 + n, quad)] : z8; \
        VR = *(const short8*)(vg + base + ((size_t)n << 9) + w0_ + quad * 8);        \
        _Pragma("unroll")                                                            \
        for (int nt = 0; nt < 8; ++nt) {                                             \
            floatx4 s0 = __builtin_amdgcn_mfma_f32_16x16x32_bf16(aq0, bkf[nt], zf, 0, 0, 0); \
            floatx4 s1 = __builtin_amdgcn_mfma_f32_16x16x32_bf16(aq1, bkf[nt], zf, 0, 0, 0); \
            const float e00 = __builtin_amdgcn_exp2f(s0[0]);                         \
            const float e01 = __builtin_amdgcn_exp2f(s0[1]);                         \
            const float e02 = __builtin_amdgcn_exp2f(s0[2]);                         \
            const float e03 = __builtin_amdgcn_exp2f(s0[3]);                         \
            const float e10 = __builtin_amdgcn_exp2f(s1[0]);                         \
            const float e11 = __builtin_amdgcn_exp2f(s1[1]);                         \
            const float e12 = __builtin_amdgcn_exp2f(s1[2]);                         \
            const float e13 = __builtin_amdgcn_exp2f(s1[3]);                         \
            SUM[0] += e00; SUM[1] += e01; SUM[2] += e02; SUM[3] += e03;              \
            SUM[4] += e10; SUM[5] += e11; SUM[6] += e12; SUM[7] += e13;              \
            *(uint2*)&Pt[wv][n][quad * 2]     = make_uint2(pkbf(e00, e01), pkbf(e02, e03)); \
            *(uint2*)&Pt[wv][n][8 + quad * 2] = make_uint2(pkbf(e10, e11), pkbf(e12, e13)); \
            __asm__ volatile("" ::: "memory");                                       \
            BP[nt] = *(const uint4*)&Pt[wv][n][quad * 4];                            \
            __asm__ volatile("" ::: "memory");                                       \
        }                                                                            \
    }

#define PUBLISH(KC, SUM)                                                             \
    {                                                                                \
        _Pragma("unroll")                                                            \
        for (int off = 1; off < 16; off <<= 1) {                                     \
            _Pragma("unroll")                                                        \
            for (int r = 0; r < 8; ++r) SUM[r] += __shfl_xor(SUM[r], off, 64);       \
        }                                                                            \
        if (n == 0) {                                                                \
            _Pragma("unroll")                                                        \
            for (int r = 0; r < 4; ++r) {                                            \
                lpartT[(KC) & 1][quad * 4 + r][wv]      = SUM[r];                    \
                lpartT[(KC) & 1][16 + quad * 4 + r][wv] = SUM[4 + r];                \
            }                                                                        \
        }                                                                            \
    }

#define PHASE2(KCP, BP, VR)                                                          \
    {                                                                                \
        const int pb_ = (KCP) & 1;                                                   \
        float rc[8];                                                                 \
        _Pragma("unroll")                                                            \
        for (int j = 0; j < 8; ++j) {                                                \
            const float4 t = *(const float4*)&lpartT[pb_][quad * 8 + j][0];          \
            rc[j] = __builtin_amdgcn_rcpf(fmaxf(t.x + t.y + t.z + t.w, 1e-30f));     \
        }                                                                            \
        union { short8 s; unsigned int u[4]; } av;                                   \
        _Pragma("unroll")                                                            \
        for (int j = 0; j < 4; ++j)                                                  \
            av.u[j] = pkbf(bf2f((unsigned short)VR[2 * j]) * rc[2 * j],              \
                           bf2f((unsigned short)VR[2 * j + 1]) * rc[2 * j + 1]);     \
        _Pragma("unroll")                                                            \
        for (int nt = 0; nt < 8; ++nt) {                                             \
            union { uint4 u; short8 s; } bpc; bpc.u = BP[nt];                        \
            acc[nt] = __builtin_amdgcn_mfma_f32_16x16x32_bf16(av.s, bpc.s, acc[nt], 0, 0, 0); \
        }                                                                            \
    }

    // ---- prologue: chunk 0 ----
    {
        float sp[8] = {0.f, 0.f, 0.f, 0.f, 0.f, 0.f, 0.f, 0.f};
        PHASE1(0, bpA, vrA, sp);
        PUBLISH(0, sp);
    }
    __syncthreads();

    // ---- steady state: chunks 1..14 in pairs (A/B ping-pong) ----
    for (int kp = 0; kp < 7; ++kp) {
        const int kc1 = 2 * kp + 1, kc2 = 2 * kp + 2;
        {
            float sb[8] = {0.f, 0.f, 0.f, 0.f, 0.f, 0.f, 0.f, 0.f};
            PHASE1(kc1, bpB, vrB, sb);
            PUBLISH(kc1, sb);
            PHASE2(kc1 - 1, bpA, vrA);       // consumes chunk 2kp
        }
        __syncthreads();
        {
            float sa[8] = {0.f, 0.f, 0.f, 0.f, 0.f, 0.f, 0.f, 0.f};
            PHASE1(kc2, bpA, vrA, sa);
            PUBLISH(kc2, sa);
            PHASE2(kc2 - 1, bpB, vrB);       // consumes chunk 2kp+1
        }
        __syncthreads();
    }

    // ---- tail: chunk 15, then drain ----
    {
        float sb[8] = {0.f, 0.f, 0.f, 0.f, 0.f, 0.f, 0.f, 0.f};
        PHASE1(15, bpB, vrB, sb);
        PUBLISH(15, sb);
        PHASE2(14, bpA, vrA);
    }
    __syncthreads();
    PHASE2(15, bpB, vrB);

#undef PHASE1
#undef PUBLISH
#undef PHASE2

    // ---- epilogue: + pe (bf16 from ws), store fp32 (write-only d_out) ----
    #pragma unroll
    for (int nt = 0; nt < 8; ++nt) {
        #pragma unroll
        for (int r = 0; r < 4; ++r) {
            const int hrow = quad * 4 + r;
            const size_t o = base + ((size_t)hrow << 9) + (v0 + nt * 16 + n);
            outg[o] = acc[nt][r] + bf2f(peg[o]);
        }
    }
}

// ---------------------------------------------------------------------------
extern "C" void kernel_launch(void* const* d_in, const int* in_sizes, int n_in,
                              void* d_out, int out_size, void* d_ws, size_t ws_size,
                              hipStream_t stream)
{
    AllIn ai;
    for (int i = 0; i < 21; ++i) ai.p[i] = d_in[i];

    unsigned short* ws  = (unsigned short*)d_ws;   // q,k,v,pe bf16: exactly 64 MiB
    float* out = (float*)d_out;                    // write-only fp32 output

    conv_kernel<<<1024, 256, 0, stream>>>(ai, ws);
    attn_kernel<<<1024, 256, 0, stream>>>(ws,
                                          ws + (size_t)Q_ELEMS,
                                          ws + 2 * (size_t)Q_ELEMS,
                                          ws + 3 * (size_t)Q_ELEMS,
                                          out);
}